// Round 6
// baseline (403.254 us; speedup 1.0000x reference)
//
#include <hip/hip_runtime.h>
#include <hip/hip_bf16.h>

#define DIM 128
#define LVL 8

typedef unsigned int u32;
typedef unsigned short u16;

using bf16x8 = __attribute__((ext_vector_type(8))) short;
using f32x4  = __attribute__((ext_vector_type(4))) float;

__device__ __forceinline__ float bf2f(u16 u) { union { u32 i; float f; } v; v.i = ((u32)u) << 16; return v.f; }
__device__ __forceinline__ u16 f2bf(float f) { __hip_bfloat16 b = __float2bfloat16(f); return *reinterpret_cast<u16*>(&b); }
__device__ __forceinline__ u32 pk2(float lo, float hi) { return (u32)f2bf(lo) | ((u32)f2bf(hi) << 16); }
__device__ __forceinline__ float sigf(float x) { return 1.f / (1.f + __expf(-x)); }
__device__ __forceinline__ float tanhfast(float x) { return 1.f - 2.f / (__expf(2.f * x) + 1.f); }

// ---- level offsets + root fan-in ----
__global__ void k_levels(const int* __restrict__ depth, int n, int* __restrict__ ofs, int* __restrict__ deg) {
  int d = threadIdx.x;
  if (d <= LVL) {
    int lo = 0, hi = n;
    while (lo < hi) { int mid = (lo + hi) >> 1; if (depth[mid] < d) lo = mid + 1; else hi = mid; }
    ofs[d] = lo;
  }
  __syncthreads();
  if (d == 0) deg[0] = ofs[2] - ofs[1];   // root's children = all of level 1
}

// ---- fan-in counts for non-root parents (depth>=2 children only; low contention) ----
__global__ void k_mark(const int* __restrict__ parent, const int* __restrict__ depth, int n,
                       int* __restrict__ deg) {
  int j = blockIdx.x * blockDim.x + threadIdx.x;
  if (j >= n) return;
  if (depth[j] < 2) return;
  int p = parent[j];
  if (p >= 0 && p < n) atomicAdd(&deg[p], 1);
}

// ---- zero hsum/fcsum rows that receive atomic accumulation (deg>=2) ----
__global__ void k_zero(const int* __restrict__ deg, int n, float* __restrict__ hsum, float* __restrict__ fcsum) {
  int row = blockIdx.x * 4 + (threadIdx.x >> 6);
  if (row >= n) return;
  if (deg[row] < 2) return;
  int l = threadIdx.x & 63;
  float2 z; z.x = 0.f; z.y = 0.f;
  *(float2*)(hsum + (size_t)row * DIM + l * 2) = z;
  *(float2*)(fcsum + (size_t)row * DIM + l * 2) = z;
}

// ---- bf16 transposed weights ----
__global__ void k_prep(const float* __restrict__ Wioux, const float* __restrict__ Wiouh,
                       const float* __restrict__ Wfx, const float* __restrict__ Wfh,
                       u16* __restrict__ WcT, u16* __restrict__ WhT, u16* __restrict__ WfhT) {
  int i = blockIdx.x * 256 + threadIdx.x;
  if (i >= 1024 * 128) return;
  int c = i >> 7, k = i & 127;
  float v; u16* dst;
  if (c < 512) {
    v = (c < 384) ? Wioux[(size_t)k * 384 + c] : Wfx[(size_t)k * 128 + (c - 384)];
    dst = &WcT[(size_t)c * 128 + k];
  } else if (c < 896) {
    int cc = c - 512; v = Wiouh[(size_t)k * 384 + cc]; dst = &WhT[(size_t)cc * 128 + k];
  } else {
    int cc = c - 896; v = Wfh[(size_t)k * 128 + cc]; dst = &WfhT[(size_t)cc * 128 + k];
  }
  *dst = f2bf(v);
}

// ---- xi = x @ [Wioux|Wfx] (MFMA bf16); xi layout [v][gate][m][nt] u16, stored from C-regs ----
__global__ __launch_bounds__(256) void k_big(const float* __restrict__ x, const u16* __restrict__ WcT,
                                             const int* __restrict__ deg, u16* __restrict__ xi, int n) {
  __shared__ __align__(16) char smem[16384 + 32768];
  char* xsb = smem;                      // 64x128 bf16 swizzled
  char* wtb = smem + 16384;              // 128x128 bf16 swizzled
  __shared__ int flg[64];
  __shared__ int s_any;
  int tid = threadIdx.x;
  int wave = tid >> 6, lane = tid & 63, m = lane & 15, kg = lane >> 4;
  int row0 = blockIdx.x * 64;
  if (tid < 64) flg[tid] = (row0 + tid < n) ? (deg[row0 + tid] > 0) : 0;
  __syncthreads();
  if (tid == 0) { int a = 0; for (int r = 0; r < 64; ++r) a |= flg[r]; s_any = a; }
  __syncthreads();
  if (!s_any) return;
  for (int i = tid; i < 64 * 16; i += 256) {
    int r = i >> 4, c8 = (i & 15) * 8;
    int gr = row0 + r;
    uint4 o = make_uint4(0u, 0u, 0u, 0u);
    if (gr < n) {
      float4 a = *(const float4*)(x + (size_t)gr * DIM + c8);
      float4 b = *(const float4*)(x + (size_t)gr * DIM + c8 + 4);
      o = make_uint4(pk2(a.x, a.y), pk2(a.z, a.w), pk2(b.x, b.y), pk2(b.z, b.w));
    }
    *(uint4*)(xsb + r * 256 + ((c8 * 2) ^ ((r & 7) << 4))) = o;
  }
  int arow = wave * 16 + m;
  for (int ci = 0; ci < 4; ++ci) {
    if (ci) __syncthreads();
    for (int i = tid; i < 128 * 16; i += 256) {
      int cl = i >> 4, k8 = (i & 15) * 8;
      uint4 v = *(const uint4*)(WcT + (size_t)(ci * 128 + cl) * 128 + k8);
      *(uint4*)(wtb + cl * 256 + ((k8 * 2) ^ ((cl & 7) << 4))) = v;
    }
    __syncthreads();
    f32x4 acc[8];
    #pragma unroll
    for (int nt = 0; nt < 8; ++nt) acc[nt] = (f32x4){0.f, 0.f, 0.f, 0.f};
    #pragma unroll
    for (int kk = 0; kk < 4; ++kk) {
      int kbyte = kk * 64 + kg * 16;
      bf16x8 a = *(const bf16x8*)(xsb + arow * 256 + (kbyte ^ ((arow & 7) << 4)));
      #pragma unroll
      for (int nt = 0; nt < 8; ++nt) {
        int col = nt * 16 + m;
        bf16x8 b = *(const bf16x8*)(wtb + col * 256 + (kbyte ^ ((col & 7) << 4)));
        acc[nt] = __builtin_amdgcn_mfma_f32_16x16x32_bf16(a, b, acc[nt], 0, 0, 0);
      }
    }
    #pragma unroll
    for (int r = 0; r < 4; ++r) {
      int rl = wave * 16 + kg * 4 + r;
      int gr = row0 + rl;
      if (gr < n && flg[rl]) {
        uint4 o = make_uint4(pk2(acc[0][r], acc[1][r]), pk2(acc[2][r], acc[3][r]),
                             pk2(acc[4][r], acc[5][r]), pk2(acc[6][r], acc[7][r]));
        *(uint4*)(xi + (((size_t)gr * 4 + ci) * 16 + m) * 8) = o;
      }
    }
  }
}

// ---- fused per-level kernel ----
__global__ __launch_bounds__(256) void k_level(const float* __restrict__ x,
    const u16* __restrict__ WhT, const u16* __restrict__ WfhT, const u16* __restrict__ xi,
    const int* __restrict__ deg, const int* __restrict__ parent, const int* __restrict__ ofs,
    float* __restrict__ hout, float* hsum, float* fcsum, int d) {
  __shared__ __align__(16) char smem[16384 + 33792];
  char* hsb = smem;                      // 64x128 bf16 swizzled
  char* wtb = smem + 16384;              // 128x128 bf16 swizzled
  float* dbuf = (float*)(smem + 16384);  // [64][132] f32 (aliases wtb)
  __shared__ int ps[64], pdeg[64], flg[64];
  __shared__ int s_uni, s_anyp;
  int v0 = ofs[d], v1 = ofs[d + 1];
  int tid = threadIdx.x;
  int wave = tid >> 6, lane = tid & 63, m = lane & 15, kg = lane >> 4;
  int arow = wave * 16 + m;
  for (int row0 = v0 + (int)blockIdx.x * 64; row0 < v1; row0 += (int)gridDim.x * 64) {
    int nrows = min(64, v1 - row0);
    if (tid < 64) {
      int ok = tid < nrows;
      int p = ok ? parent[row0 + tid] : 0;
      ps[tid] = p;
      pdeg[tid] = ok ? deg[p] : 0;
      flg[tid] = ok ? (deg[row0 + tid] > 0) : 0;
    }
    __syncthreads();
    if (tid == 0) {
      int a = 0; for (int r = 0; r < nrows; ++r) a |= flg[r];
      s_anyp = a;
      int u = 1, p0 = ps[0];
      for (int r = 1; r < nrows; ++r) if (ps[r] != p0) { u = 0; break; }
      s_uni = u && (pdeg[0] >= 2);
    }
    __syncthreads();
    f32x4 acc[3][8];
    #pragma unroll
    for (int ci = 0; ci < 3; ++ci)
      #pragma unroll
      for (int nt = 0; nt < 8; ++nt) acc[ci][nt] = (f32x4){0.f, 0.f, 0.f, 0.f};
    if (s_anyp) {
      for (int i = tid; i < 64 * 16; i += 256) {
        int r = i >> 4, c8 = (i & 15) * 8;
        uint4 o = make_uint4(0u, 0u, 0u, 0u);
        if (r < nrows) {
          const float* hp = hsum + (size_t)(row0 + r) * DIM + c8;
          float4 a = *(const float4*)hp; float4 b = *(const float4*)(hp + 4);
          o = make_uint4(pk2(a.x, a.y), pk2(a.z, a.w), pk2(b.x, b.y), pk2(b.z, b.w));
        }
        *(uint4*)(hsb + r * 256 + ((c8 * 2) ^ ((r & 7) << 4))) = o;
      }
      #pragma unroll
      for (int ci = 0; ci < 3; ++ci) {
        for (int i = tid; i < 128 * 16; i += 256) {
          int cl = i >> 4, k8 = (i & 15) * 8;
          uint4 v = *(const uint4*)(WhT + (size_t)(ci * 128 + cl) * 128 + k8);
          *(uint4*)(wtb + cl * 256 + ((k8 * 2) ^ ((cl & 7) << 4))) = v;
        }
        __syncthreads();
        #pragma unroll
        for (int kk = 0; kk < 4; ++kk) {
          int kbyte = kk * 64 + kg * 16;
          bf16x8 a = *(const bf16x8*)(hsb + arow * 256 + (kbyte ^ ((arow & 7) << 4)));
          #pragma unroll
          for (int nt = 0; nt < 8; ++nt) {
            int col = nt * 16 + m;
            bf16x8 b = *(const bf16x8*)(wtb + col * 256 + (kbyte ^ ((col & 7) << 4)));
            acc[ci][nt] = __builtin_amdgcn_mfma_f32_16x16x32_bf16(a, b, acc[ci][nt], 0, 0, 0);
          }
        }
        __syncthreads();
      }
    }
    // ---- epilogue: gates; h to global; h-bf16 into hsb ----
    float cc[8][4];
    #pragma unroll
    for (int r = 0; r < 4; ++r) {
      int rl = wave * 16 + kg * 4 + r;
      int grow = row0 + rl;
      if (rl < nrows) {
        bool leaf = !flg[rl];
        uint4 qi = *(const uint4*)(xi + (((size_t)grow * 4 + 0) * 16 + m) * 8);
        uint4 qo = *(const uint4*)(xi + (((size_t)grow * 4 + 1) * 16 + m) * 8);
        uint4 qu = *(const uint4*)(xi + (((size_t)grow * 4 + 2) * 16 + m) * 8);
        float4 fa = *(const float4*)(fcsum + ((size_t)grow * 16 + m) * 8);
        float4 fb = *(const float4*)(fcsum + ((size_t)grow * 16 + m) * 8 + 4);
        #pragma unroll
        for (int nt = 0; nt < 8; ++nt) {
          int col = nt * 16 + m;
          float xv = x[(size_t)grow * DIM + col];
          float iv = bf2f(((const u16*)&qi)[nt]) + acc[0][nt][r];
          float ov = bf2f(((const u16*)&qo)[nt]) + acc[1][nt][r];
          float uv = bf2f(((const u16*)&qu)[nt]) + acc[2][nt][r];
          float fcv = (nt < 4) ? ((const float*)&fa)[nt] : ((const float*)&fb)[nt - 4];
          float ci_ = fcv + sigf(iv) * tanhfast(uv);
          float hv = leaf ? xv : sigf(ov) * tanhfast(ci_);
          float cv = leaf ? tanhfast(xv) : ci_;
          cc[nt][r] = cv;
          hout[(size_t)grow * DIM + col] = hv;
          *(u16*)(hsb + rl * 256 + ((2 * col) ^ ((rl & 7) << 4))) = f2bf(hv);
        }
      } else {
        #pragma unroll
        for (int nt = 0; nt < 8; ++nt) {
          cc[nt][r] = 0.f;
          *(u16*)(hsb + rl * 256 + ((2 * (nt * 16 + m)) ^ ((rl & 7) << 4))) = 0;
        }
      }
    }
    // ---- f-gate MFMA + scatter ----
    for (int i = tid; i < 128 * 16; i += 256) {
      int cl = i >> 4, k8 = (i & 15) * 8;
      uint4 v = *(const uint4*)(WfhT + (size_t)cl * 128 + k8);
      *(uint4*)(wtb + cl * 256 + ((k8 * 2) ^ ((cl & 7) << 4))) = v;
    }
    __syncthreads();
    f32x4 fp[8];
    #pragma unroll
    for (int nt = 0; nt < 8; ++nt) fp[nt] = (f32x4){0.f, 0.f, 0.f, 0.f};
    #pragma unroll
    for (int kk = 0; kk < 4; ++kk) {
      int kbyte = kk * 64 + kg * 16;
      bf16x8 a = *(const bf16x8*)(hsb + arow * 256 + (kbyte ^ ((arow & 7) << 4)));
      #pragma unroll
      for (int nt = 0; nt < 8; ++nt) {
        int col = nt * 16 + m;
        bf16x8 b = *(const bf16x8*)(wtb + col * 256 + (kbyte ^ ((col & 7) << 4)));
        fp[nt] = __builtin_amdgcn_mfma_f32_16x16x32_bf16(a, b, fp[nt], 0, 0, 0);
      }
    }
    __syncthreads();                     // wtb consumed -> dbuf writable
    if (s_uni) {
      int p0 = ps[0];
      uint4 qf = *(const uint4*)(xi + (((size_t)p0 * 4 + 3) * 16 + m) * 8);
      #pragma unroll
      for (int r = 0; r < 4; ++r) {
        int rl = wave * 16 + kg * 4 + r;
        bool act = rl < nrows;
        #pragma unroll
        for (int nt = 0; nt < 8; ++nt) {
          float fc = act ? sigf(bf2f(((const u16*)&qf)[nt]) + fp[nt][r]) * cc[nt][r] : 0.f;
          dbuf[rl * 132 + nt * 16 + m] = fc;
        }
      }
      __syncthreads();
      if (tid < 128) {
        float sh = 0.f, sf = 0.f;
        #pragma unroll 8
        for (int r = 0; r < 64; ++r) {
          sh += bf2f(*(const u16*)(hsb + r * 256 + ((2 * tid) ^ ((r & 7) << 4))));
          sf += dbuf[r * 132 + tid];
        }
        atomicAdd(&hsum[(size_t)p0 * DIM + tid], sh);
        atomicAdd(&fcsum[((size_t)p0 * 16 + (tid & 15)) * 8 + (tid >> 4)], sf);
      }
    } else {
      #pragma unroll
      for (int r = 0; r < 4; ++r) {
        int rl = wave * 16 + kg * 4 + r;
        if (rl >= nrows) continue;
        int p = ps[rl], dg = pdeg[rl];
        uint4 qf = *(const uint4*)(xi + (((size_t)p * 4 + 3) * 16 + m) * 8);
        float fcn[8], hv8[8];
        #pragma unroll
        for (int nt = 0; nt < 8; ++nt) {
          fcn[nt] = sigf(bf2f(((const u16*)&qf)[nt]) + fp[nt][r]) * cc[nt][r];
          hv8[nt] = bf2f(*(const u16*)(hsb + rl * 256 + ((2 * (nt * 16 + m)) ^ ((rl & 7) << 4))));
        }
        if (dg == 1) {
          #pragma unroll
          for (int nt = 0; nt < 8; ++nt)
            hsum[(size_t)p * DIM + nt * 16 + m] = hv8[nt];
          float4 s0 = make_float4(fcn[0], fcn[1], fcn[2], fcn[3]);
          float4 s1 = make_float4(fcn[4], fcn[5], fcn[6], fcn[7]);
          *(float4*)(fcsum + ((size_t)p * 16 + m) * 8) = s0;
          *(float4*)(fcsum + ((size_t)p * 16 + m) * 8 + 4) = s1;
        } else {
          #pragma unroll
          for (int nt = 0; nt < 8; ++nt) {
            atomicAdd(&hsum[(size_t)p * DIM + nt * 16 + m], hv8[nt]);
            atomicAdd(&fcsum[((size_t)p * 16 + m) * 8 + nt], fcn[nt]);
          }
        }
      }
    }
    __syncthreads();
  }
}

// ---- root (node 0) ----
__global__ void k_root(const float* __restrict__ x, const u16* __restrict__ WhT,
                       const u16* __restrict__ xi, const int* __restrict__ deg,
                       const float* __restrict__ hsum, const float* __restrict__ fcsum,
                       float* __restrict__ hout) {
  __shared__ float hs[128];
  __shared__ float pre[384];
  int tid = threadIdx.x;
  if (deg[0] == 0) { if (tid < 128) hout[tid] = x[tid]; return; }
  if (tid < 128) hs[tid] = hsum[tid];
  __syncthreads();
  for (int c = tid; c < 384; c += 256) {
    float a = 0.f;
    const u16* wr = WhT + (size_t)c * 128;
    for (int k = 0; k < 128; ++k) a += hs[k] * bf2f(wr[k]);
    pre[c] = a;
  }
  __syncthreads();
  if (tid < 128) {
    int m = tid & 15, nt = tid >> 4;
    float iv = bf2f(xi[((size_t)0 * 16 + m) * 8 + nt])   + pre[tid];
    float ov = bf2f(xi[((size_t)1 * 16 + m) * 8 + nt])   + pre[128 + tid];
    float uv = bf2f(xi[((size_t)2 * 16 + m) * 8 + nt])   + pre[256 + tid];
    float fcv = fcsum[((size_t)m) * 8 + nt];
    float ci_ = fcv + sigf(iv) * tanhfast(uv);
    hout[tid] = sigf(ov) * tanhfast(ci_);
  }
}

extern "C" void kernel_launch(void* const* d_in, const int* in_sizes, int n_in,
                              void* d_out, int out_size, void* d_ws, size_t ws_size,
                              hipStream_t stream) {
  const float* x    = (const float*)d_in[0];
  const int* parent = (const int*)d_in[1];
  const int* depth  = (const int*)d_in[2];
  const float* Wioux = (const float*)d_in[3];
  const float* Wiouh = (const float*)d_in[4];
  const float* Wfx   = (const float*)d_in[5];
  const float* Wfh   = (const float*)d_in[6];
  int n = in_sizes[0] / DIM;
  float* h = (float*)d_out;

  u16*   WcT  = (u16*)d_ws;                            // 512*128
  u16*   WhT  = WcT + 512 * 128;                       // 384*128
  u16*   WfhT = WhT + 384 * 128;                       // 128*128
  u16*   xi   = WfhT + 128 * 128;                      // n*512  ([v][gate][m][nt])
  float* hsum = (float*)(xi + (size_t)n * 512);        // n*128  (row-major)
  float* fcsum = hsum + (size_t)n * DIM;               // n*128  ([v][m][nt])
  int*   deg  = (int*)(fcsum + (size_t)n * DIM);       // n
  int*   ofs  = deg + n;                               // LVL+1

  hipMemsetAsync(deg, 0, (size_t)n * sizeof(int), stream);
  k_prep<<<512, 256, 0, stream>>>(Wioux, Wiouh, Wfx, Wfh, WcT, WhT, WfhT);
  k_levels<<<1, 32, 0, stream>>>(depth, n, ofs, deg);
  k_mark<<<(n + 255) / 256, 256, 0, stream>>>(parent, depth, n, deg);
  k_zero<<<(n + 3) / 4, 256, 0, stream>>>(deg, n, hsum, fcsum);
  k_big<<<(n + 63) / 64, 256, 0, stream>>>(x, WcT, deg, xi, n);

  for (int d = LVL - 1; d >= 1; --d)
    k_level<<<256, 256, 0, stream>>>(x, WhT, WfhT, xi, deg, parent, ofs, h, hsum, fcsum, d);
  k_root<<<1, 256, 0, stream>>>(x, WhT, xi, deg, hsum, fcsum, h);
}